// Round 2
// baseline (95.476 us; speedup 1.0000x reference)
//
#include <hip/hip_runtime.h>
#include <hip/hip_bf16.h>

typedef short short8 __attribute__((ext_vector_type(8)));
typedef float f32x4 __attribute__((ext_vector_type(4)));

__device__ __forceinline__ unsigned short f2bf(float f) {
    union { float f; unsigned int i; } v; v.f = f;
    unsigned int i = v.i;
    unsigned int r = (i + 0x7fffu + ((i >> 16) & 1u)) >> 16;   // RNE
    return (unsigned short)r;
}

// One block per node (b,n). 256 threads. N=256, B=2 fixed by problem shape.
__global__ __launch_bounds__(256, 2)
void tpconv_kernel(const float* __restrict__ node_attr,   // [B,256,64]
                   const float* __restrict__ edge_attr,   // [B,256,256,32]
                   const float* __restrict__ edge_sh,     // [B,256,256,4]
                   const float* __restrict__ mask,        // [B,256]
                   const float* __restrict__ wlis,        // [16,16]
                   const float* __restrict__ wliv,        // [16,16]
                   const float* __restrict__ fc_w1,       // [32,32]
                   const float* __restrict__ fc_b1,       // [32]
                   const float* __restrict__ fc_w2,       // [32,1024]
                   const float* __restrict__ fc_b2,       // [1024]
                   const float* __restrict__ wlos,        // [16,16]
                   const float* __restrict__ wlov,        // [16,16]
                   float* __restrict__ out)               // [B,256,64]
{
    const int node = blockIdx.x;      // b*256 + n
    const int b = node >> 8;
    const int n = node & 255;
    const int t = threadIdx.x;

    __shared__ __align__(16) unsigned short s_ea[256 * 32];   // 16 KB edge_attr row (bf16)
    __shared__ __align__(16) unsigned short s_w1t[32 * 32];   // fc_w1 transposed [f][k] (bf16)
    __shared__ __align__(16) float s_wc[4 * 256];             // per-edge weights (sh_s, sh_v xyz)*mask
    __shared__ float s_b1[32];
    __shared__ float s_wmask[4];
    __shared__ __align__(16) float s_wp[512];                 // per-wave moment partials [w][c][f]
    __shared__ float s_wp0[16];                               // per-wave bias-moment partials [w][c]
    __shared__ __align__(16) float s_mom[128];                // moments [c][f]
    __shared__ float s_mom0[4];
    __shared__ float s_scale;
    __shared__ float s_sin[16];                               // s_in
    __shared__ float s_vin[48];                               // v_in[o][x] at o*3+x
    __shared__ __align__(16) float s_eff[8 * 256];            // 8 effective 16x16 matrices
    __shared__ float s_pre[16];
    __shared__ float s_prev[48];

    // ---------------- Phase 0: staging ----------------
    {
        const float4* src = (const float4*)(edge_attr + (size_t)node * (256 * 32));
        #pragma unroll
        for (int it = 0; it < 8; ++it) {
            float4 v = src[it * 256 + t];
            ushort4 u;
            u.x = f2bf(v.x); u.y = f2bf(v.y); u.z = f2bf(v.z); u.w = f2bf(v.w);
            *(ushort4*)&s_ea[(it * 256 + t) * 4] = u;
        }
    }
    {
        float mk = mask[(b << 8) + t];
        float ms = mk;
        ms += __shfl_xor(ms, 1);  ms += __shfl_xor(ms, 2);  ms += __shfl_xor(ms, 4);
        ms += __shfl_xor(ms, 8);  ms += __shfl_xor(ms, 16); ms += __shfl_xor(ms, 32);
        if ((t & 63) == 0) s_wmask[t >> 6] = ms;
        float excl = (t == n) ? 0.0f : mk;   // mask out self-edge
        const float4 sh4 = *(const float4*)(edge_sh + ((size_t)node * 256 + t) * 4);
        s_wc[0 * 256 + t] = excl * sh4.x;
        s_wc[1 * 256 + t] = excl * sh4.y;
        s_wc[2 * 256 + t] = excl * sh4.z;
        s_wc[3 * 256 + t] = excl * sh4.w;
    }
    {
        #pragma unroll
        for (int j = 0; j < 4; ++j) {
            int e = t * 4 + j;
            int f = e >> 5, k = e & 31;
            s_w1t[e] = f2bf(fc_w1[k * 32 + f]);   // s_w1t[f*32+k] = W1[k][f]
        }
        if (t < 32) s_b1[t] = fc_b1[t];
    }
    if (t >= 64 && t < 80) {
        int o = t - 64;
        const float* na = node_attr + (size_t)node * 64;
        float a = 0.f;
        #pragma unroll
        for (int i = 0; i < 16; ++i) a += na[i] * wlis[i * 16 + o];
        s_sin[o] = a * 0.25f;    // / sqrt(16)
    } else if (t >= 80 && t < 128) {
        int idx = t - 80;
        int o = idx / 3, x = idx - o * 3;
        const float* na = node_attr + (size_t)node * 64;
        float a = 0.f;
        #pragma unroll
        for (int i = 0; i < 16; ++i) a += na[16 + i * 3 + x] * wliv[i * 16 + o];
        s_vin[idx] = a * 0.25f;
    }
    __syncthreads();

    // ------- Phase 1: h = relu(ea@W1 + b1) via MFMA, fold weighted moments -------
    {
        const int wv = t >> 6;          // wave 0..3
        const int ln = t & 63;
        const int q  = ln >> 4;         // quad
        const int fc = ln & 15;
        // B-fragments: lane holds B[k][n]=W1[k][f] for f=fc(+16), k=q*8+j  -> W1T rows
        short8 bf0 = *(const short8*)&s_w1t[fc * 32 + q * 8];
        short8 bf1 = *(const short8*)&s_w1t[(16 + fc) * 32 + q * 8];
        float b1a = s_b1[fc], b1b = s_b1[16 + fc];
        float pmc[4][2] = {{0,0},{0,0},{0,0},{0,0}};
        float pm0[4] = {0,0,0,0};
        #pragma unroll
        for (int tt = 0; tt < 4; ++tt) {
            const int T = wv * 4 + tt;          // edge tile (16 edges)
            // A-fragment: lane holds A[m=fc][k=q*8+j] -> row T*16+fc of s_ea
            short8 af = *(const short8*)&s_ea[(T * 16 + fc) * 32 + q * 8];
            f32x4 z = {0.f, 0.f, 0.f, 0.f};
            f32x4 acc0 = __builtin_amdgcn_mfma_f32_16x16x32_bf16(af, bf0, z, 0, 0, 0);
            f32x4 acc1 = __builtin_amdgcn_mfma_f32_16x16x32_bf16(af, bf1, z, 0, 0, 0);
            // C layout: lane(q,fc) reg r -> h[edge=T*16+q*4+r][f=fc(+16)]
            f32x4 w0 = *(const f32x4*)&s_wc[0 * 256 + T * 16 + q * 4];
            f32x4 w1 = *(const f32x4*)&s_wc[1 * 256 + T * 16 + q * 4];
            f32x4 w2 = *(const f32x4*)&s_wc[2 * 256 + T * 16 + q * 4];
            f32x4 w3 = *(const f32x4*)&s_wc[3 * 256 + T * 16 + q * 4];
            #pragma unroll
            for (int r = 0; r < 4; ++r) {
                float h0 = acc0[r] + b1a; h0 = h0 > 0.f ? h0 : 0.f;
                float h1 = acc1[r] + b1b; h1 = h1 > 0.f ? h1 : 0.f;
                float wr0 = w0[r], wr1 = w1[r], wr2 = w2[r], wr3 = w3[r];
                pmc[0][0] += h0 * wr0; pmc[0][1] += h1 * wr0;
                pmc[1][0] += h0 * wr1; pmc[1][1] += h1 * wr1;
                pmc[2][0] += h0 * wr2; pmc[2][1] += h1 * wr2;
                pmc[3][0] += h0 * wr3; pmc[3][1] += h1 * wr3;
                pm0[0] += wr0; pm0[1] += wr1; pm0[2] += wr2; pm0[3] += wr3;
            }
        }
        // reduce across quads (lanes differing in bits 4,5 share f)
        #pragma unroll
        for (int c = 0; c < 4; ++c) {
            #pragma unroll
            for (int ft = 0; ft < 2; ++ft) {
                float v = pmc[c][ft];
                v += __shfl_xor(v, 16);
                v += __shfl_xor(v, 32);
                if (q == 0) s_wp[(wv * 4 + c) * 32 + ft * 16 + fc] = v;
            }
            float v0 = pm0[c];
            v0 += __shfl_xor(v0, 16);
            v0 += __shfl_xor(v0, 32);
            if (ln == 0) s_wp0[wv * 4 + c] = v0;
        }
    }
    __syncthreads();

    // ---------------- Phase 2: combine wave partials ----------------
    if (t < 128) {
        int c = t >> 5, f = t & 31;
        s_mom[c * 32 + f] = s_wp[(0 + c) * 32 + f] + s_wp[(4 + c) * 32 + f]
                          + s_wp[(8 + c) * 32 + f] + s_wp[(12 + c) * 32 + f];
    } else if (t == 128) {
        #pragma unroll
        for (int c = 0; c < 4; ++c)
            s_mom0[c] = s_wp0[c] + s_wp0[4 + c] + s_wp0[8 + c] + s_wp0[12 + c];
    } else if (t == 129) {
        float ds = s_wmask[0] + s_wmask[1] + s_wmask[2] + s_wmask[3] - 1.0f;
        s_scale = 0.17677669529663687f / ds;   // inv_fan / dsum
    }
    __syncthreads();

    // ------- Phase 3: effective matrices Eff = Mom @ W2blk + Mom0*b2blk -------
    {
        const int e8 = t >> 5;        // which eff matrix 0..7
        const int q8 = t & 31;
        const int col0 = q8 * 8;      // 8 consecutive cols of the 256-col block
        int c, wblk;
        if (e8 == 0)      { c = 0;      wblk = 0; }   // ss
        else if (e8 <= 3) { c = e8;     wblk = 1; }   // vv_x
        else if (e8 <= 6) { c = e8 - 3; wblk = 2; }   // sv_x
        else              { c = 0;      wblk = 3; }   // vs
        float momf[32];
        #pragma unroll
        for (int f = 0; f < 32; ++f) momf[f] = s_mom[c * 32 + f];
        float m0 = s_mom0[c];
        const float* w2g = fc_w2 + wblk * 256 + col0;
        const float* b2g = fc_b2 + wblk * 256 + col0;
        float acc[8];
        float4 bbA = *(const float4*)b2g;
        float4 bbB = *(const float4*)(b2g + 4);
        acc[0] = m0 * bbA.x; acc[1] = m0 * bbA.y; acc[2] = m0 * bbA.z; acc[3] = m0 * bbA.w;
        acc[4] = m0 * bbB.x; acc[5] = m0 * bbB.y; acc[6] = m0 * bbB.z; acc[7] = m0 * bbB.w;
        #pragma unroll
        for (int f = 0; f < 32; ++f) {
            float4 wA = *(const float4*)(w2g + f * 1024);
            float4 wB = *(const float4*)(w2g + f * 1024 + 4);
            float mf = momf[f];
            acc[0] += mf * wA.x; acc[1] += mf * wA.y; acc[2] += mf * wA.z; acc[3] += mf * wA.w;
            acc[4] += mf * wB.x; acc[5] += mf * wB.y; acc[6] += mf * wB.z; acc[7] += mf * wB.w;
        }
        #pragma unroll
        for (int j = 0; j < 8; ++j) s_eff[e8 * 256 + col0 + j] = acc[j];
    }
    __syncthreads();

    // ---------------- Phase 4a: contract with s_in / v_in ----------------
    {
        const float inv_s3 = 0.5773502691896258f;
        if (t < 16) {
            int o = t;
            float a = 0.f;
            #pragma unroll
            for (int i = 0; i < 16; ++i) a += s_sin[i] * s_eff[0 * 256 + i * 16 + o];
            float bs = 0.f;
            #pragma unroll
            for (int x = 0; x < 3; ++x)
                #pragma unroll
                for (int i = 0; i < 16; ++i)
                    bs += s_vin[i * 3 + x] * s_eff[(1 + x) * 256 + i * 16 + o];
            s_pre[o] = (a + bs * inv_s3) * s_scale;
        } else if (t < 64) {
            int idx = t - 16;
            int o = idx / 3, x = idx - o * 3;
            float a = 0.f;
            #pragma unroll
            for (int i = 0; i < 16; ++i) a += s_sin[i] * s_eff[(4 + x) * 256 + i * 16 + o];
            float bs = 0.f;
            #pragma unroll
            for (int i = 0; i < 16; ++i) bs += s_vin[i * 3 + x] * s_eff[7 * 256 + i * 16 + o];
            s_prev[idx] = (a + bs) * s_scale;
        }
    }
    __syncthreads();

    // ---------------- Phase 4b: output linear + residual ----------------
    if (t < 16) {
        int o = t;
        float a = 0.f;
        #pragma unroll
        for (int i = 0; i < 16; ++i) a += s_pre[i] * wlos[i * 16 + o];
        const float* na = node_attr + (size_t)node * 64;
        out[(size_t)node * 64 + o] = a * 0.25f + na[o];
    } else if (t < 64) {
        int idx = t - 16;
        int o = idx / 3, x = idx - o * 3;
        float a = 0.f;
        #pragma unroll
        for (int i = 0; i < 16; ++i) a += s_prev[i * 3 + x] * wlov[i * 16 + o];
        const float* na = node_attr + (size_t)node * 64;
        out[(size_t)node * 64 + 16 + idx] = a * 0.25f + na[16 + idx];
    }
}

extern "C" void kernel_launch(void* const* d_in, const int* in_sizes, int n_in,
                              void* d_out, int out_size, void* d_ws, size_t ws_size,
                              hipStream_t stream) {
    (void)n_in; (void)d_ws; (void)ws_size; (void)out_size;
    const float* node_attr = (const float*)d_in[0];
    const float* edge_attr = (const float*)d_in[1];
    const float* edge_sh   = (const float*)d_in[2];
    const float* maskp     = (const float*)d_in[3];
    const float* wlis      = (const float*)d_in[4];
    const float* wliv      = (const float*)d_in[5];
    const float* fc_w1     = (const float*)d_in[6];
    const float* fc_b1     = (const float*)d_in[7];
    const float* fc_w2     = (const float*)d_in[8];
    const float* fc_b2     = (const float*)d_in[9];
    const float* wlos      = (const float*)d_in[10];
    const float* wlov      = (const float*)d_in[11];
    float* outp = (float*)d_out;

    int nodes = in_sizes[0] / 64;   // B*N = 512
    tpconv_kernel<<<dim3(nodes), dim3(256), 0, stream>>>(
        node_attr, edge_attr, edge_sh, maskp, wlis, wliv,
        fc_w1, fc_b1, fc_w2, fc_b2, wlos, wlov, outp);
}